// Round 3
// baseline (429.702 us; speedup 1.0000x reference)
//
#include <hip/hip_runtime.h>
#include <stdint.h>

#define NN 50000
#define NE 500000
#define NEPAD 500032              // NE rounded up to 64
#define NTILES (NEPAD / 64)       // 7813 edge tiles
#define EGRID 1024                // 4 blocks/CU exactly; grid-stride over tiles
#define NT_BLOCKS ((NN + 63) / 64)            // 782 (k_hp / k_out grids)
#define DEG_STRIDE (NT_BLOCKS * 256)          // 200192
#define NBLK_N ((NN + 255) / 256)             // 196

typedef short bf16x8 __attribute__((ext_vector_type(8)));
typedef float f32x4 __attribute__((ext_vector_type(4)));
typedef unsigned short u16;
typedef unsigned short u16x4 __attribute__((ext_vector_type(4)));
typedef unsigned short u16x8 __attribute__((ext_vector_type(8)));
typedef unsigned int u32x4 __attribute__((ext_vector_type(4)));

__device__ __forceinline__ u16 f2b(float x) {
  uint32_t u = __builtin_bit_cast(uint32_t, x);
  return (u16)((u + 0x7fffu + ((u >> 16) & 1u)) >> 16);
}
__device__ __forceinline__ float b2f(uint32_t lo16) {
  return __builtin_bit_cast(float, lo16 << 16);
}

// LDS-only barrier: order DS ops, leave global loads in flight (prefetch
// survives the barrier; __syncthreads would conservatively drain vmcnt).
#define EBAR()                                            \
  {                                                       \
    asm volatile("s_waitcnt lgkmcnt(0)" ::: "memory");    \
    __builtin_amdgcn_s_barrier();                         \
  }

// JAX threefry2x32, key = jax.random.key(42) -> (0, 42)
__device__ __forceinline__ void threefry(uint32_t x0, uint32_t x1,
                                         uint32_t& o0, uint32_t& o1) {
  const uint32_t k0 = 0u, k1 = 42u, k2 = 0u ^ 42u ^ 0x1BD11BDAu;
  x0 += k0; x1 += k1;
#define TFR(r) { x0 += x1; x1 = (x1 << r) | (x1 >> (32 - r)); x1 ^= x0; }
  TFR(13) TFR(15) TFR(26) TFR(6)
  x0 += k1; x1 += k2 + 1u;
  TFR(17) TFR(29) TFR(16) TFR(24)
  x0 += k2; x1 += k0 + 2u;
  TFR(13) TFR(15) TFR(26) TFR(6)
  x0 += k0; x1 += k1 + 3u;
  TFR(17) TFR(29) TFR(16) TFR(24)
  x0 += k1; x1 += k2 + 4u;
  TFR(13) TFR(15) TFR(26) TFR(6)
  x0 += k2; x1 += k0 + 5u;
#undef TFR
  o0 = x0; o1 = x1;
}

__device__ __forceinline__ bool jax_keep(uint32_t j) {
  uint32_t o0, o1;
  threefry(0u, j, o0, o1);
  uint32_t bits = o0 ^ o1;
  float u = __builtin_bit_cast(float, (bits >> 9) | 0x3f800000u) - 1.0f;
  return u < 0.9f;
}

// ---- weight images: W*Img[d][k] = bf16(W[k][d]) (transposed, B-operand ready)
__global__ __launch_bounds__(256) void k_prep(const float* __restrict__ Wmsg,
                                              const float* __restrict__ Wlin,
                                              u16* __restrict__ WhImg,
                                              u16* __restrict__ WcImg,
                                              u16* __restrict__ WlImg) {
  const int t = threadIdx.x, b = blockIdx.x;
  if (b == 0) {
#pragma unroll
    for (int it = 0; it < 16; ++it) {
      int g = t + (it << 8);
      int d = g >> 5, k4 = (g & 31) << 2;
      u16x4 v = {f2b(Wmsg[(k4 + 0) * 128 + d]), f2b(Wmsg[(k4 + 1) * 128 + d]),
                 f2b(Wmsg[(k4 + 2) * 128 + d]), f2b(Wmsg[(k4 + 3) * 128 + d])};
      *(u16x4*)&WhImg[(d << 7) + k4] = v;
    }
  } else if (b == 1) {
#pragma unroll
    for (int it = 0; it < 8; ++it) {
      int g = t + (it << 8);
      int d = g >> 4, k4 = (g & 15) << 2;
      u16x4 v = {f2b(Wmsg[(128 + k4 + 0) * 128 + d]), f2b(Wmsg[(128 + k4 + 1) * 128 + d]),
                 f2b(Wmsg[(128 + k4 + 2) * 128 + d]), f2b(Wmsg[(128 + k4 + 3) * 128 + d])};
      *(u16x4*)&WcImg[(d << 6) + k4] = v;
    }
  } else {
#pragma unroll
    for (int it = 0; it < 16; ++it) {
      int g = t + (it << 8);
      int d = g >> 5, k4 = (g & 31) << 2;
      u16x4 v = {f2b(Wlin[(k4 + 0) * 128 + d]), f2b(Wlin[(k4 + 1) * 128 + d]),
                 f2b(Wlin[(k4 + 2) * 128 + d]), f2b(Wlin[(k4 + 3) * 128 + d])};
      *(u16x4*)&WlImg[(d << 7) + k4] = v;
    }
  }
}

// ---- hierarchical scan ----
__global__ __launch_bounds__(256) void k_scan1(const uint32_t* __restrict__ deg,
                                               uint32_t* __restrict__ ex,
                                               uint32_t* __restrict__ bsum) {
  __shared__ uint32_t s[256];
  int t = threadIdx.x;
  int i = blockIdx.x * 256 + t;
  uint32_t v = (i < NN) ? deg[i] : 0u;
  s[t] = v;
  __syncthreads();
#pragma unroll
  for (int off = 1; off < 256; off <<= 1) {
    uint32_t y = (t >= off) ? s[t - off] : 0u;
    __syncthreads();
    s[t] += y;
    __syncthreads();
  }
  if (i < NN) ex[i] = s[t] - v;
  if (t == 255) bsum[blockIdx.x] = s[255];
}

__global__ __launch_bounds__(256) void k_scan2(const uint32_t* __restrict__ bsum,
                                               uint32_t* __restrict__ boff) {
  __shared__ uint32_t s[256];
  int t = threadIdx.x;
  uint32_t v = (t < NBLK_N) ? bsum[t] : 0u;
  s[t] = v;
  __syncthreads();
#pragma unroll
  for (int off = 1; off < 256; off <<= 1) {
    uint32_t y = (t >= off) ? s[t - off] : 0u;
    __syncthreads();
    s[t] += y;
    __syncthreads();
  }
  boff[t] = s[t] - v;
}

__global__ __launch_bounds__(256) void k_scan3(const uint32_t* __restrict__ ex,
                                               const uint32_t* __restrict__ boff,
                                               uint32_t* __restrict__ cursor) {
  int i = blockIdx.x * 256 + threadIdx.x;
  if (i < NN) cursor[i] = ex[i] + boff[blockIdx.x];
}

// k_perm: index-only scatter. perm[pos]=e, sd[pos]=src|(dst<<16).
__global__ __launch_bounds__(256) void k_perm(const int* __restrict__ ei,
                                              uint32_t* __restrict__ cursor,
                                              int* __restrict__ perm,
                                              uint32_t* __restrict__ sd) {
  int i = blockIdx.x * 256 + threadIdx.x;
  if (i < NE) {
    uint32_t s = (uint32_t)ei[i], d = (uint32_t)ei[NE + i];
    uint32_t pos = atomicAdd(&cursor[d], 1u);
    perm[pos] = i;
    sd[pos] = s | (d << 16);
  }
}

// ---- prefetch state for k_edge3's cross-tile pipeline ----
struct Pf {
  f32x4 a00, a01, a10, a11;  // A gather: (row, g) 32B and (row+32, g) 32B
  uint32_t sdv;              // src|(dst<<16) for slot s = t>>2
  int dst;                   // -1 if slot invalid
  bool v1;                   // slot valid
};

__device__ __forceinline__ void pf_issue_a(Pf& p, long e0, int t,
                                           const int* __restrict__ perm,
                                           const uint32_t* __restrict__ sd,
                                           const float* __restrict__ attr,
                                           const float* __restrict__ tim) {
  const int row = t >> 3, g = t & 7;
  long sg0 = e0 + row, sg1 = e0 + row + 32;
  int ea = perm[sg0 < NE ? sg0 : 0];   // clamp: pad rows read real data,
  int eb = perm[sg1 < NE ? sg1 : 0];   // excluded later via dst=-1
  const float* pa = (g < 4) ? attr + ((size_t)ea << 5) + (g << 3)
                            : tim + ((size_t)ea << 5) + ((g & 3) << 3);
  const float* pb = (g < 4) ? attr + ((size_t)eb << 5) + (g << 3)
                            : tim + ((size_t)eb << 5) + ((g & 3) << 3);
  p.a00 = *(const f32x4*)pa;
  p.a01 = *(const f32x4*)(pa + 4);
  p.a10 = *(const f32x4*)pb;
  p.a11 = *(const f32x4*)(pb + 4);
  const int s = t >> 2;
  long sgs = e0 + s;
  p.v1 = sgs < NE;
  p.sdv = sd[p.v1 ? sgs : 0];
  p.dst = p.v1 ? (int)(p.sdv >> 16) : -1;
}

__device__ __forceinline__ void pf_write_a(const Pf& p, int t,
                                           u16* __restrict__ A,
                                           int* __restrict__ sdst) {
  const int row = t >> 3, g = t & 7;
  u16x8 b0 = {f2b(p.a00[0]), f2b(p.a00[1]), f2b(p.a00[2]), f2b(p.a00[3]),
              f2b(p.a01[0]), f2b(p.a01[1]), f2b(p.a01[2]), f2b(p.a01[3])};
  *(u16x8*)&A[(row << 6) + ((g ^ (row & 7)) << 3)] = b0;
  const int row1 = row + 32;
  u16x8 b1 = {f2b(p.a10[0]), f2b(p.a10[1]), f2b(p.a10[2]), f2b(p.a10[3]),
              f2b(p.a11[0]), f2b(p.a11[1]), f2b(p.a11[2]), f2b(p.a11[3])};
  *(u16x8*)&A[(row1 << 6) + ((g ^ (row1 & 7)) << 3)] = b1;
  if ((t & 3) == 0) sdst[t >> 2] = p.dst;
}

// K2: fused f32 gather + MFMA + relu(+Hp) + segmented reduce, software-
// pipelined across tiles (grid-stride, next-tile gathers in registers).
__global__ __launch_bounds__(256, 4) void k_edge3(const int* __restrict__ perm,
                                                  const uint32_t* __restrict__ sd,
                                                  const float* __restrict__ attr,
                                                  const float* __restrict__ tim,
                                                  const u16* __restrict__ WcImg,
                                                  const u16* __restrict__ Hp,
                                                  float* __restrict__ acc) {
  __shared__ union { u16 A[64 * 64]; float C[64 * 128]; } lds;  // 32 KB
  __shared__ int sdst[64];
  const int t = threadIdx.x;
  const int lane = t & 63, w = t >> 6;
  const int quad = lane >> 4, lr = lane & 15;
  const int s = t >> 2, q = t & 3;

  int tile = blockIdx.x;
  Pf pf;
  pf_issue_a(pf, (long)tile << 6, t, perm, sd, attr, tim);

  while (true) {
    const int ntile = tile + EGRID;
    const bool more = ntile < NTILES;

    pf_write_a(pf, t, lds.A, sdst);
    Pf pf2;
    if (more) pf_issue_a(pf2, (long)ntile << 6, t, perm, sd, attr, tim);

    // Hp gather for CURRENT tile; consumed 3 barriers later in relu.
    const int src = pf.v1 ? (int)(pf.sdv & 0xffffu) : 0;
    const u32x4* hp4 = (const u32x4*)(Hp + ((size_t)src << 7) + (q << 5));
    u32x4 h0 = hp4[0], h1 = hp4[1], h2 = hp4[2], h3 = hp4[3];

    EBAR();  // A visible

    f32x4 c[4][2];
#pragma unroll
    for (int i = 0; i < 4; ++i)
#pragma unroll
      for (int j = 0; j < 2; ++j) { f32x4 z = {0.f, 0.f, 0.f, 0.f}; c[i][j] = z; }
#pragma unroll
    for (int ks = 0; ks < 64; ks += 32) {
      const int gi = (ks >> 3) + quad;
      bf16x8 a[4], b[2];
#pragma unroll
      for (int i = 0; i < 4; ++i) {
        int row = (i << 4) + lr;
        a[i] = *(const bf16x8*)&lds.A[(row << 6) + ((gi ^ (row & 7)) << 3)];
      }
#pragma unroll
      for (int j = 0; j < 2; ++j) {
        int col = (w << 5) + (j << 4) + lr;
        b[j] = *(const bf16x8*)&WcImg[(col << 6) + (gi << 3)];
      }
#pragma unroll
      for (int i = 0; i < 4; ++i)
#pragma unroll
        for (int j = 0; j < 2; ++j)
          c[i][j] = __builtin_amdgcn_mfma_f32_16x16x32_bf16(a[i], b[j], c[i][j], 0, 0, 0);
    }

    EBAR();  // A consumed; C region may be written

#pragma unroll
    for (int i = 0; i < 4; ++i)
#pragma unroll
      for (int j = 0; j < 2; ++j)
#pragma unroll
        for (int r = 0; r < 4; ++r) {
          int row = (i << 4) + (quad << 2) + r;
          int col = (w << 5) + (j << 4) + lr;
          lds.C[(row << 7) + ((((col >> 2) ^ (row & 31)) << 2) + (col & 3))] = c[i][j][r];
        }

    EBAR();  // C visible

    // stage 1: msg = relu(P + Hp[src]); thread (s,q) owns cols q*32..+31
    if (pf.v1) {
#pragma unroll
      for (int g = 0; g < 8; ++g) {
        const u32x4 hw = (g < 2) ? h0 : (g < 4) ? h1 : (g < 6) ? h2 : h3;
        int cb = (q << 5) + (g << 2);
        float* p = &lds.C[(s << 7) + ((((cb >> 2) ^ (s & 31)) << 2))];
        f32x4 cv = *(const f32x4*)p;
        uint32_t w0 = hw[(g & 1) << 1];
        uint32_t w1 = hw[((g & 1) << 1) + 1];
        cv[0] = fmaxf(cv[0] + b2f(w0 & 0xffffu), 0.f);
        cv[1] = fmaxf(cv[1] + b2f(w0 >> 16), 0.f);
        cv[2] = fmaxf(cv[2] + b2f(w1 & 0xffffu), 0.f);
        cv[3] = fmaxf(cv[3] + b2f(w1 >> 16), 0.f);
        *(f32x4*)p = cv;
      }
    }

    EBAR();  // relu'd C visible

    // stage 2: segmented reduction, 2 halves x 128 cols
    {
      const int col = t & 127, half = t >> 7;
      const int beg = half << 5, end = beg + 32;
      int cur = sdst[beg];
      float sum = 0.f;
      int runstart = beg;
      for (int ss = beg; ss < end; ++ss) {
        int d = sdst[ss];
        if (d != cur) {
          if (cur >= 0) {
            float* p = acc + ((size_t)cur << 7) + col;
            if (runstart == beg) unsafeAtomicAdd(p, sum);
            else *p = sum;
          }
          cur = d; sum = 0.f; runstart = ss;
        }
        sum += lds.C[(ss << 7) + ((((col >> 2) ^ (ss & 31)) << 2) + (col & 3))];
      }
      if (cur >= 0) unsafeAtomicAdd(acc + ((size_t)cur << 7) + col, sum);
    }

    EBAR();  // C consumed; next iteration may overwrite A/sdst

    if (!more) break;
    pf = pf2;
    tile = ntile;
  }
}

// K1: Hp = bf16(hidden @ W_msg[0:128,:] + b_msg), 64-row tiles, B from global
// WhImg (L1-hot). LDS = A only (16 KB). Fused deg count.
__global__ __launch_bounds__(256) void k_hp(const float* __restrict__ hidden,
                                            const u16* __restrict__ WhImg,
                                            const float* __restrict__ bmsg,
                                            const int* __restrict__ ei,
                                            uint32_t* __restrict__ deg,
                                            u16* __restrict__ Hp) {
  __shared__ u16 sA[64 * 128];
  const int t = threadIdx.x;
  const int row0 = blockIdx.x << 6;
  for (int i = blockIdx.x * 256 + t; i < NE; i += DEG_STRIDE)
    atomicAdd(&deg[ei[NE + i]], 1u);
#pragma unroll
  for (int it = 0; it < 8; ++it) {
    int li = t + (it << 8);
    int row = li >> 5, c4 = li & 31;
    int n = row0 + row;
    f32x4 v = {0.f, 0.f, 0.f, 0.f};
    if (n < NN) v = *(const f32x4*)(hidden + ((size_t)n << 7) + (c4 << 2));
    u16x4 b = {f2b(v[0]), f2b(v[1]), f2b(v[2]), f2b(v[3])};
    *(u16x4*)&sA[(row << 7) + ((((c4 >> 1) ^ (row & 15)) << 3) + ((c4 & 1) << 2))] = b;
  }
  __syncthreads();
  const int lane = t & 63, w = t >> 6;
  const int quad = lane >> 4, lr = lane & 15;
  f32x4 c[4][2];
#pragma unroll
  for (int i = 0; i < 4; ++i)
#pragma unroll
    for (int j = 0; j < 2; ++j) { f32x4 z = {0.f, 0.f, 0.f, 0.f}; c[i][j] = z; }
#pragma unroll
  for (int ks = 0; ks < 128; ks += 32) {
    const int gi = (ks >> 3) + quad;
    bf16x8 a[4], b[2];
#pragma unroll
    for (int i = 0; i < 4; ++i) {
      int row = (i << 4) + lr;
      a[i] = *(const bf16x8*)&sA[(row << 7) + ((gi ^ (row & 15)) << 3)];
    }
#pragma unroll
    for (int j = 0; j < 2; ++j) {
      int col = (w << 5) + (j << 4) + lr;
      b[j] = *(const bf16x8*)&WhImg[(col << 7) + (gi << 3)];
    }
#pragma unroll
    for (int i = 0; i < 4; ++i)
#pragma unroll
      for (int j = 0; j < 2; ++j)
        c[i][j] = __builtin_amdgcn_mfma_f32_16x16x32_bf16(a[i], b[j], c[i][j], 0, 0, 0);
  }
#pragma unroll
  for (int j = 0; j < 2; ++j) {
    int d = (w << 5) + (j << 4) + lr;
    float bias = bmsg[d];
#pragma unroll
    for (int i = 0; i < 4; ++i) {
      int nb = row0 + (i << 4) + (quad << 2);
#pragma unroll
      for (int r = 0; r < 4; ++r) {
        int n = nb + r;
        if (n < NN) Hp[((size_t)n << 7) + d] = f2b(c[i][j][r] + bias);
      }
    }
  }
}

// K3 (in-place): out = dropout(relu(LN((acc+boundary) @ W_lin + b_lin)))
// 64-row tiles, B from global WlImg, LDS 32 KB union.
__global__ __launch_bounds__(256) void k_out(float* accout,
                                             const float* __restrict__ bnd,
                                             const u16* __restrict__ WlImg,
                                             const float* __restrict__ blin,
                                             const float* __restrict__ gam,
                                             const float* __restrict__ bet) {
  __shared__ union { u16 A[64 * 128]; float C[64 * 128]; } lds;  // 32 KB
  const int t = threadIdx.x;
  const int row0 = blockIdx.x << 6;
#pragma unroll
  for (int it = 0; it < 8; ++it) {
    int li = t + (it << 8);
    int row = li >> 5, c4 = li & 31;
    int n = row0 + row;
    f32x4 v = {0.f, 0.f, 0.f, 0.f};
    if (n < NN) {
      f32x4 a = *(const f32x4*)(accout + ((size_t)n << 7) + (c4 << 2));
      f32x4 b = *(const f32x4*)(bnd + ((size_t)n << 7) + (c4 << 2));
      v = a + b;
    }
    u16x4 bb = {f2b(v[0]), f2b(v[1]), f2b(v[2]), f2b(v[3])};
    *(u16x4*)&lds.A[(row << 7) + ((((c4 >> 1) ^ (row & 15)) << 3) + ((c4 & 1) << 2))] = bb;
  }
  __syncthreads();
  const int lane = t & 63, w = t >> 6;
  const int quad = lane >> 4, lr = lane & 15;
  f32x4 c[4][2];
#pragma unroll
  for (int i = 0; i < 4; ++i)
#pragma unroll
    for (int j = 0; j < 2; ++j) { f32x4 z = {0.f, 0.f, 0.f, 0.f}; c[i][j] = z; }
#pragma unroll
  for (int ks = 0; ks < 128; ks += 32) {
    const int gi = (ks >> 3) + quad;
    bf16x8 a[4], b[2];
#pragma unroll
    for (int i = 0; i < 4; ++i) {
      int row = (i << 4) + lr;
      a[i] = *(const bf16x8*)&lds.A[(row << 7) + ((gi ^ (row & 15)) << 3)];
    }
#pragma unroll
    for (int j = 0; j < 2; ++j) {
      int col = (w << 5) + (j << 4) + lr;
      b[j] = *(const bf16x8*)&WlImg[(col << 7) + (gi << 3)];
    }
#pragma unroll
    for (int i = 0; i < 4; ++i)
#pragma unroll
      for (int j = 0; j < 2; ++j)
        c[i][j] = __builtin_amdgcn_mfma_f32_16x16x32_bf16(a[i], b[j], c[i][j], 0, 0, 0);
  }
  __syncthreads();  // all waves done reading A before C overwrites
#pragma unroll
  for (int i = 0; i < 4; ++i)
#pragma unroll
    for (int j = 0; j < 2; ++j)
#pragma unroll
      for (int r = 0; r < 4; ++r) {
        int row = (i << 4) + (quad << 2) + r;
        int col = (w << 5) + (j << 4) + lr;
        lds.C[(row << 7) + ((((col >> 2) ^ (row & 31)) << 2) + (col & 3))] = c[i][j][r];
      }
  __syncthreads();
  // LN + relu + dropout: 4 threads/row, thread q owns cols q*32..+31
  const int row = t >> 2, q = t & 3;
  const int n = row0 + row;
  float s1 = 0.f, s2 = 0.f;
  if (n < NN) {
#pragma unroll
    for (int g = 0; g < 8; ++g) {
      int g5 = (q << 3) + g;
      f32x4 cv = *(const f32x4*)&lds.C[(row << 7) + ((g5 ^ (row & 31)) << 2)];
      f32x4 bl = *(const f32x4*)(blin + (g5 << 2));
#pragma unroll
      for (int m = 0; m < 4; ++m) {
        float x = cv[m] + bl[m];
        s1 += x; s2 += x * x;
      }
    }
  }
  s1 += __shfl_xor(s1, 1, 64); s1 += __shfl_xor(s1, 2, 64);
  s2 += __shfl_xor(s2, 1, 64); s2 += __shfl_xor(s2, 2, 64);
  if (n < NN) {
    const float mean = s1 * 0.0078125f;
    const float var = s2 * 0.0078125f - mean * mean;
    const float inv = 1.0f / sqrtf(var + 1e-5f);
#pragma unroll
    for (int g = 0; g < 8; ++g) {
      int g5 = (q << 3) + g;
      int d0 = g5 << 2;
      f32x4 cv = *(const f32x4*)&lds.C[(row << 7) + ((g5 ^ (row & 31)) << 2)];
      f32x4 bl = *(const f32x4*)(blin + d0);
      f32x4 gm = *(const f32x4*)(gam + d0);
      f32x4 bb = *(const f32x4*)(bet + d0);
      f32x4 o;
#pragma unroll
      for (int m = 0; m < 4; ++m) {
        float x = cv[m] + bl[m];
        float y = fmaxf((x - mean) * inv * gm[m] + bb[m], 0.f);
        uint32_t jj = ((uint32_t)n << 7) + (uint32_t)(d0 + m);
        o[m] = jax_keep(jj) ? (y * (1.0f / 0.9f)) : 0.0f;
      }
      *(f32x4*)(accout + ((size_t)n << 7) + d0) = o;
    }
  }
}

extern "C" void kernel_launch(void* const* d_in, const int* in_sizes, int n_in,
                              void* d_out, int out_size, void* d_ws, size_t ws_size,
                              hipStream_t stream) {
  (void)in_sizes; (void)n_in; (void)out_size; (void)ws_size;
  const float* hidden = (const float*)d_in[0];
  const int*   ei     = (const int*)d_in[1];
  const float* attr   = (const float*)d_in[2];
  const float* tim    = (const float*)d_in[3];
  const float* bnd    = (const float*)d_in[4];
  const float* Wmsg   = (const float*)d_in[5];
  const float* bmsg   = (const float*)d_in[6];
  const float* Wlin   = (const float*)d_in[7];
  const float* blin   = (const float*)d_in[8];
  const float* gam    = (const float*)d_in[9];
  const float* bet    = (const float*)d_in[10];

  float* acc = (float*)d_out;  // [N,128] f32 accumulator, finalized in-place

  char* ws = (char*)d_ws;
  u16*      Hp     = (u16*)(ws + 0);              // 12,800,000
  u16*      WhImg  = (u16*)(ws + 12800000);       //     32,768
  u16*      WcImg  = (u16*)(ws + 12832768);       //     16,384
  u16*      WlImg  = (u16*)(ws + 12849152);       //     32,768
  uint32_t* deg    = (uint32_t*)(ws + 12881920);  //    200,000
  uint32_t* cursor = (uint32_t*)(ws + 13081920);  //    200,000
  uint32_t* bsum   = (uint32_t*)(ws + 13281920);  //      1,024
  uint32_t* boff   = (uint32_t*)(ws + 13282944);  //      1,024
  uint32_t* ex     = (uint32_t*)(ws + 13283968);  //    200,000
  uint32_t* sd     = (uint32_t*)(ws + 13483968);  //  2,000,128 (NEPAD*4)
  int*      perm   = (int*)(ws + 15484096);       //  2,000,128 (NEPAD*4)
  // total 17,484,224 bytes

  hipMemsetAsync(deg, 0, (size_t)NN * 4, stream);
  hipMemsetAsync(acc, 0, (size_t)NN * 128 * 4, stream);

  k_prep <<<dim3(3), dim3(256), 0, stream>>>(Wmsg, Wlin, WhImg, WcImg, WlImg);
  k_hp   <<<dim3(NT_BLOCKS), dim3(256), 0, stream>>>(hidden, WhImg, bmsg, ei, deg, Hp);
  k_scan1<<<dim3(NBLK_N), dim3(256), 0, stream>>>(deg, ex, bsum);
  k_scan2<<<dim3(1), dim3(256), 0, stream>>>(bsum, boff);
  k_scan3<<<dim3(NBLK_N), dim3(256), 0, stream>>>(ex, boff, cursor);
  k_perm <<<dim3((NE + 255) / 256), dim3(256), 0, stream>>>(ei, cursor, perm, sd);
  k_edge3<<<dim3(EGRID), dim3(256), 0, stream>>>(perm, sd, attr, tim, WcImg, Hp, acc);
  k_out  <<<dim3(NT_BLOCKS), dim3(256), 0, stream>>>(acc, bnd, WlImg, blin, gam, bet);
}

// Round 4
// 362.280 us; speedup vs baseline: 1.1861x; 1.1861x over previous
//
#include <hip/hip_runtime.h>
#include <stdint.h>

#define NN 50000
#define NE 500000
#define NEPAD 500032              // NE rounded up to 64
#define SPB 64
#define NT_BLOCKS ((NN + 63) / 64)            // 782 (k_hp / k_out grids)
#define DEG_STRIDE (NT_BLOCKS * 256)          // 200192
#define NBLK_N ((NN + 255) / 256)             // 196

typedef short bf16x8 __attribute__((ext_vector_type(8)));
typedef float f32x4 __attribute__((ext_vector_type(4)));
typedef unsigned short u16;
typedef unsigned short u16x4 __attribute__((ext_vector_type(4)));
typedef unsigned short u16x8 __attribute__((ext_vector_type(8)));
typedef unsigned int u32x4 __attribute__((ext_vector_type(4)));

__device__ __forceinline__ u16 f2b(float x) {
  uint32_t u = __builtin_bit_cast(uint32_t, x);
  return (u16)((u + 0x7fffu + ((u >> 16) & 1u)) >> 16);
}
__device__ __forceinline__ float b2f(uint32_t lo16) {
  return __builtin_bit_cast(float, lo16 << 16);
}

// JAX threefry2x32, key = jax.random.key(42) -> (0, 42)
__device__ __forceinline__ void threefry(uint32_t x0, uint32_t x1,
                                         uint32_t& o0, uint32_t& o1) {
  const uint32_t k0 = 0u, k1 = 42u, k2 = 0u ^ 42u ^ 0x1BD11BDAu;
  x0 += k0; x1 += k1;
#define TFR(r) { x0 += x1; x1 = (x1 << r) | (x1 >> (32 - r)); x1 ^= x0; }
  TFR(13) TFR(15) TFR(26) TFR(6)
  x0 += k1; x1 += k2 + 1u;
  TFR(17) TFR(29) TFR(16) TFR(24)
  x0 += k2; x1 += k0 + 2u;
  TFR(13) TFR(15) TFR(26) TFR(6)
  x0 += k0; x1 += k1 + 3u;
  TFR(17) TFR(29) TFR(16) TFR(24)
  x0 += k1; x1 += k2 + 4u;
  TFR(13) TFR(15) TFR(26) TFR(6)
  x0 += k2; x1 += k0 + 5u;
#undef TFR
  o0 = x0; o1 = x1;
}

__device__ __forceinline__ bool jax_keep(uint32_t j) {
  uint32_t o0, o1;
  threefry(0u, j, o0, o1);
  uint32_t bits = o0 ^ o1;
  float u = __builtin_bit_cast(float, (bits >> 9) | 0x3f800000u) - 1.0f;
  return u < 0.9f;
}

// ---- weight images: W*Img[d][k] = bf16(W[k][d]) (transposed, B-operand ready)
__global__ __launch_bounds__(256) void k_prep(const float* __restrict__ Wmsg,
                                              const float* __restrict__ Wlin,
                                              u16* __restrict__ WhImg,
                                              u16* __restrict__ WcImg,
                                              u16* __restrict__ WlImg) {
  const int t = threadIdx.x, b = blockIdx.x;
  if (b == 0) {
#pragma unroll
    for (int it = 0; it < 16; ++it) {
      int g = t + (it << 8);
      int d = g >> 5, k4 = (g & 31) << 2;
      u16x4 v = {f2b(Wmsg[(k4 + 0) * 128 + d]), f2b(Wmsg[(k4 + 1) * 128 + d]),
                 f2b(Wmsg[(k4 + 2) * 128 + d]), f2b(Wmsg[(k4 + 3) * 128 + d])};
      *(u16x4*)&WhImg[(d << 7) + k4] = v;
    }
  } else if (b == 1) {
#pragma unroll
    for (int it = 0; it < 8; ++it) {
      int g = t + (it << 8);
      int d = g >> 4, k4 = (g & 15) << 2;
      u16x4 v = {f2b(Wmsg[(128 + k4 + 0) * 128 + d]), f2b(Wmsg[(128 + k4 + 1) * 128 + d]),
                 f2b(Wmsg[(128 + k4 + 2) * 128 + d]), f2b(Wmsg[(128 + k4 + 3) * 128 + d])};
      *(u16x4*)&WcImg[(d << 6) + k4] = v;
    }
  } else {
#pragma unroll
    for (int it = 0; it < 16; ++it) {
      int g = t + (it << 8);
      int d = g >> 5, k4 = (g & 31) << 2;
      u16x4 v = {f2b(Wlin[(k4 + 0) * 128 + d]), f2b(Wlin[(k4 + 1) * 128 + d]),
                 f2b(Wlin[(k4 + 2) * 128 + d]), f2b(Wlin[(k4 + 3) * 128 + d])};
      *(u16x4*)&WlImg[(d << 7) + k4] = v;
    }
  }
}

// ---- hierarchical scan ----
__global__ __launch_bounds__(256) void k_scan1(const uint32_t* __restrict__ deg,
                                               uint32_t* __restrict__ ex,
                                               uint32_t* __restrict__ bsum) {
  __shared__ uint32_t s[256];
  int t = threadIdx.x;
  int i = blockIdx.x * 256 + t;
  uint32_t v = (i < NN) ? deg[i] : 0u;
  s[t] = v;
  __syncthreads();
#pragma unroll
  for (int off = 1; off < 256; off <<= 1) {
    uint32_t y = (t >= off) ? s[t - off] : 0u;
    __syncthreads();
    s[t] += y;
    __syncthreads();
  }
  if (i < NN) ex[i] = s[t] - v;
  if (t == 255) bsum[blockIdx.x] = s[255];
}

__global__ __launch_bounds__(256) void k_scan2(const uint32_t* __restrict__ bsum,
                                               uint32_t* __restrict__ boff) {
  __shared__ uint32_t s[256];
  int t = threadIdx.x;
  uint32_t v = (t < NBLK_N) ? bsum[t] : 0u;
  s[t] = v;
  __syncthreads();
#pragma unroll
  for (int off = 1; off < 256; off <<= 1) {
    uint32_t y = (t >= off) ? s[t - off] : 0u;
    __syncthreads();
    s[t] += y;
    __syncthreads();
  }
  boff[t] = s[t] - v;
}

__global__ __launch_bounds__(256) void k_scan3(const uint32_t* __restrict__ ex,
                                               const uint32_t* __restrict__ boff,
                                               uint32_t* __restrict__ cursor) {
  int i = blockIdx.x * 256 + threadIdx.x;
  if (i < NN) cursor[i] = ex[i] + boff[blockIdx.x];
}

// k_perm: index-only scatter. perm[pos]=e, sd[pos]=src|(dst<<16).
__global__ __launch_bounds__(256) void k_perm(const int* __restrict__ ei,
                                              uint32_t* __restrict__ cursor,
                                              int* __restrict__ perm,
                                              uint32_t* __restrict__ sd) {
  int i = blockIdx.x * 256 + threadIdx.x;
  if (i < NE) {
    uint32_t s = (uint32_t)ei[i], d = (uint32_t)ei[NE + i];
    uint32_t pos = atomicAdd(&cursor[d], 1u);
    perm[pos] = i;
    sd[pos] = s | (d << 16);
  }
}

// K2: A gathered directly from attr/tim f32 (bf16-converted in-kernel,
// XOR-swizzled LDS). Single-phase 64x128 C spill (round-1 structure).
__global__ __launch_bounds__(256, 4) void k_edge3(const int* __restrict__ perm,
                                                  const uint32_t* __restrict__ sd,
                                                  const float* __restrict__ attr,
                                                  const float* __restrict__ tim,
                                                  const u16* __restrict__ WcImg,
                                                  const u16* __restrict__ Hp,
                                                  float* __restrict__ acc) {
  __shared__ union { u16 A[64 * 64]; float C[64 * 128]; } lds;  // 32 KB
  __shared__ int sdst[64];
  const int t = threadIdx.x;
  const long e0 = (long)blockIdx.x << 6;

  // stage A: gather f32 rows (8 threads/row, 32 B each), convert, swizzle
#pragma unroll
  for (int it = 0; it < 2; ++it) {
    int li = t + (it << 8);
    int row = li >> 3, g = li & 7;
    long sg = e0 + row;
    const bool vld = sg < NE;
    int e = 0;
    if (vld) e = perm[sg];
    const float* src8 = (g < 4) ? (attr + ((size_t)e << 5) + (g << 3))
                                : (tim + ((size_t)e << 5) + ((g - 4) << 3));
    f32x4 v0 = {0.f, 0.f, 0.f, 0.f}, v1 = {0.f, 0.f, 0.f, 0.f};
    if (vld) {
      v0 = *(const f32x4*)src8;
      v1 = *(const f32x4*)(src8 + 4);
    }
    u16x8 b = {f2b(v0[0]), f2b(v0[1]), f2b(v0[2]), f2b(v0[3]),
               f2b(v1[0]), f2b(v1[1]), f2b(v1[2]), f2b(v1[3])};
    *(u16x8*)&lds.A[(row << 6) + ((g ^ (row & 7)) << 3)] = b;
  }
  // per-slot src/dst + Hp register prefetch: 4 threads/slot, 32-col slices
  const int s = t >> 2, q = t & 3;
  const long sg1 = e0 + s;
  const bool v1 = sg1 < NE;
  int src = 0, dstn = -1;
  if (v1) {
    uint32_t sdv = sd[sg1];
    src = (int)(sdv & 0xffffu);
    dstn = (int)(sdv >> 16);
  }
  u32x4 hp[4];
  if (v1) {
    const u32x4* hp4 = (const u32x4*)(Hp + ((size_t)src << 7) + (q << 5));
#pragma unroll
    for (int g = 0; g < 4; ++g) hp[g] = hp4[g];
  }
  if (q == 0) sdst[s] = v1 ? dstn : -1;
  __syncthreads();

  const int lane = t & 63, w = t >> 6;
  const int quad = lane >> 4, lr = lane & 15;
  f32x4 c[4][2];
#pragma unroll
  for (int i = 0; i < 4; ++i)
#pragma unroll
    for (int j = 0; j < 2; ++j) { f32x4 z = {0.f, 0.f, 0.f, 0.f}; c[i][j] = z; }
#pragma unroll
  for (int ks = 0; ks < 64; ks += 32) {
    const int gi = (ks >> 3) + quad;
    bf16x8 a[4], b[2];
#pragma unroll
    for (int i = 0; i < 4; ++i) {
      int row = (i << 4) + lr;
      a[i] = *(const bf16x8*)&lds.A[(row << 6) + ((gi ^ (row & 7)) << 3)];
    }
#pragma unroll
    for (int j = 0; j < 2; ++j) {
      int col = (w << 5) + (j << 4) + lr;
      b[j] = *(const bf16x8*)&WcImg[(col << 6) + (gi << 3)];
    }
#pragma unroll
    for (int i = 0; i < 4; ++i)
#pragma unroll
      for (int j = 0; j < 2; ++j)
        c[i][j] = __builtin_amdgcn_mfma_f32_16x16x32_bf16(a[i], b[j], c[i][j], 0, 0, 0);
  }
  __syncthreads();
#pragma unroll
  for (int i = 0; i < 4; ++i)
#pragma unroll
    for (int j = 0; j < 2; ++j)
#pragma unroll
      for (int r = 0; r < 4; ++r) {
        int row = (i << 4) + (quad << 2) + r;
        int col = (w << 5) + (j << 4) + lr;
        lds.C[(row << 7) + ((((col >> 2) ^ (row & 31)) << 2) + (col & 3))] = c[i][j][r];
      }
  __syncthreads();
  // stage 1: msg = relu(P + Hp[src]); thread (s,q) owns cols q*32..+31
  if (v1) {
#pragma unroll
    for (int g = 0; g < 8; ++g) {
      int cb = (q << 5) + (g << 2);
      float* p = &lds.C[(s << 7) + ((((cb >> 2) ^ (s & 31)) << 2))];
      f32x4 cv = *(const f32x4*)p;
      uint32_t w0 = hp[g >> 1][(g & 1) << 1];
      uint32_t w1 = hp[g >> 1][((g & 1) << 1) + 1];
      cv[0] = fmaxf(cv[0] + b2f(w0 & 0xffffu), 0.f);
      cv[1] = fmaxf(cv[1] + b2f(w0 >> 16), 0.f);
      cv[2] = fmaxf(cv[2] + b2f(w1 & 0xffffu), 0.f);
      cv[3] = fmaxf(cv[3] + b2f(w1 >> 16), 0.f);
      *(f32x4*)p = cv;
    }
  }
  __syncthreads();
  // stage 2: segmented reduction, 2 halves x 128 cols
  {
    const int col = t & 127, half = t >> 7;
    const int beg = half << 5, end = beg + 32;
    int cur = sdst[beg];
    float sum = 0.f;
    int runstart = beg;
    for (int ss = beg; ss < end; ++ss) {
      int d = sdst[ss];
      if (d != cur) {
        if (cur >= 0) {
          float* p = acc + ((size_t)cur << 7) + col;
          if (runstart == beg) unsafeAtomicAdd(p, sum);
          else *p = sum;
        }
        cur = d; sum = 0.f; runstart = ss;
      }
      sum += lds.C[(ss << 7) + ((((col >> 2) ^ (ss & 31)) << 2) + (col & 3))];
    }
    if (cur >= 0) unsafeAtomicAdd(acc + ((size_t)cur << 7) + col, sum);
  }
}

// K1: Hp = bf16(hidden @ W_msg[0:128,:] + b_msg), 64-row tiles, B from global
// WhImg (L1-hot). LDS = A only (16 KB). Fused deg count.
__global__ __launch_bounds__(256) void k_hp(const float* __restrict__ hidden,
                                            const u16* __restrict__ WhImg,
                                            const float* __restrict__ bmsg,
                                            const int* __restrict__ ei,
                                            uint32_t* __restrict__ deg,
                                            u16* __restrict__ Hp) {
  __shared__ u16 sA[64 * 128];
  const int t = threadIdx.x;
  const int row0 = blockIdx.x << 6;
  for (int i = blockIdx.x * 256 + t; i < NE; i += DEG_STRIDE)
    atomicAdd(&deg[ei[NE + i]], 1u);
#pragma unroll
  for (int it = 0; it < 8; ++it) {
    int li = t + (it << 8);
    int row = li >> 5, c4 = li & 31;
    int n = row0 + row;
    f32x4 v = {0.f, 0.f, 0.f, 0.f};
    if (n < NN) v = *(const f32x4*)(hidden + ((size_t)n << 7) + (c4 << 2));
    u16x4 b = {f2b(v[0]), f2b(v[1]), f2b(v[2]), f2b(v[3])};
    *(u16x4*)&sA[(row << 7) + ((((c4 >> 1) ^ (row & 15)) << 3) + ((c4 & 1) << 2))] = b;
  }
  __syncthreads();
  const int lane = t & 63, w = t >> 6;
  const int quad = lane >> 4, lr = lane & 15;
  f32x4 c[4][2];
#pragma unroll
  for (int i = 0; i < 4; ++i)
#pragma unroll
    for (int j = 0; j < 2; ++j) { f32x4 z = {0.f, 0.f, 0.f, 0.f}; c[i][j] = z; }
#pragma unroll
  for (int ks = 0; ks < 128; ks += 32) {
    const int gi = (ks >> 3) + quad;
    bf16x8 a[4], b[2];
#pragma unroll
    for (int i = 0; i < 4; ++i) {
      int row = (i << 4) + lr;
      a[i] = *(const bf16x8*)&sA[(row << 7) + ((gi ^ (row & 15)) << 3)];
    }
#pragma unroll
    for (int j = 0; j < 2; ++j) {
      int col = (w << 5) + (j << 4) + lr;
      b[j] = *(const bf16x8*)&WhImg[(col << 7) + (gi << 3)];
    }
#pragma unroll
    for (int i = 0; i < 4; ++i)
#pragma unroll
      for (int j = 0; j < 2; ++j)
        c[i][j] = __builtin_amdgcn_mfma_f32_16x16x32_bf16(a[i], b[j], c[i][j], 0, 0, 0);
  }
#pragma unroll
  for (int j = 0; j < 2; ++j) {
    int d = (w << 5) + (j << 4) + lr;
    float bias = bmsg[d];
#pragma unroll
    for (int i = 0; i < 4; ++i) {
      int nb = row0 + (i << 4) + (quad << 2);
#pragma unroll
      for (int r = 0; r < 4; ++r) {
        int n = nb + r;
        if (n < NN) Hp[((size_t)n << 7) + d] = f2b(c[i][j][r] + bias);
      }
    }
  }
}

// K3 (in-place): out = dropout(relu(LN((acc+boundary) @ W_lin + b_lin)))
// 64-row tiles, B from global WlImg, LDS 32 KB union.
__global__ __launch_bounds__(256) void k_out(float* accout,
                                             const float* __restrict__ bnd,
                                             const u16* __restrict__ WlImg,
                                             const float* __restrict__ blin,
                                             const float* __restrict__ gam,
                                             const float* __restrict__ bet) {
  __shared__ union { u16 A[64 * 128]; float C[64 * 128]; } lds;  // 32 KB
  const int t = threadIdx.x;
  const int row0 = blockIdx.x << 6;
#pragma unroll
  for (int it = 0; it < 8; ++it) {
    int li = t + (it << 8);
    int row = li >> 5, c4 = li & 31;
    int n = row0 + row;
    f32x4 v = {0.f, 0.f, 0.f, 0.f};
    if (n < NN) {
      f32x4 a = *(const f32x4*)(accout + ((size_t)n << 7) + (c4 << 2));
      f32x4 b = *(const f32x4*)(bnd + ((size_t)n << 7) + (c4 << 2));
      v = a + b;
    }
    u16x4 bb = {f2b(v[0]), f2b(v[1]), f2b(v[2]), f2b(v[3])};
    *(u16x4*)&lds.A[(row << 7) + ((((c4 >> 1) ^ (row & 15)) << 3) + ((c4 & 1) << 2))] = bb;
  }
  __syncthreads();
  const int lane = t & 63, w = t >> 6;
  const int quad = lane >> 4, lr = lane & 15;
  f32x4 c[4][2];
#pragma unroll
  for (int i = 0; i < 4; ++i)
#pragma unroll
    for (int j = 0; j < 2; ++j) { f32x4 z = {0.f, 0.f, 0.f, 0.f}; c[i][j] = z; }
#pragma unroll
  for (int ks = 0; ks < 128; ks += 32) {
    const int gi = (ks >> 3) + quad;
    bf16x8 a[4], b[2];
#pragma unroll
    for (int i = 0; i < 4; ++i) {
      int row = (i << 4) + lr;
      a[i] = *(const bf16x8*)&lds.A[(row << 7) + ((gi ^ (row & 15)) << 3)];
    }
#pragma unroll
    for (int j = 0; j < 2; ++j) {
      int col = (w << 5) + (j << 4) + lr;
      b[j] = *(const bf16x8*)&WlImg[(col << 7) + (gi << 3)];
    }
#pragma unroll
    for (int i = 0; i < 4; ++i)
#pragma unroll
      for (int j = 0; j < 2; ++j)
        c[i][j] = __builtin_amdgcn_mfma_f32_16x16x32_bf16(a[i], b[j], c[i][j], 0, 0, 0);
  }
  __syncthreads();  // all waves done reading A before C overwrites
#pragma unroll
  for (int i = 0; i < 4; ++i)
#pragma unroll
    for (int j = 0; j < 2; ++j)
#pragma unroll
      for (int r = 0; r < 4; ++r) {
        int row = (i << 4) + (quad << 2) + r;
        int col = (w << 5) + (j << 4) + lr;
        lds.C[(row << 7) + ((((col >> 2) ^ (row & 31)) << 2) + (col & 3))] = c[i][j][r];
      }
  __syncthreads();
  // LN + relu + dropout: 4 threads/row, thread q owns cols q*32..+31
  const int row = t >> 2, q = t & 3;
  const int n = row0 + row;
  float s1 = 0.f, s2 = 0.f;
  if (n < NN) {
#pragma unroll
    for (int g = 0; g < 8; ++g) {
      int g5 = (q << 3) + g;
      f32x4 cv = *(const f32x4*)&lds.C[(row << 7) + ((g5 ^ (row & 31)) << 2)];
      f32x4 bl = *(const f32x4*)(blin + (g5 << 2));
#pragma unroll
      for (int m = 0; m < 4; ++m) {
        float x = cv[m] + bl[m];
        s1 += x; s2 += x * x;
      }
    }
  }
  s1 += __shfl_xor(s1, 1, 64); s1 += __shfl_xor(s1, 2, 64);
  s2 += __shfl_xor(s2, 1, 64); s2 += __shfl_xor(s2, 2, 64);
  if (n < NN) {
    const float mean = s1 * 0.0078125f;
    const float var = s2 * 0.0078125f - mean * mean;
    const float inv = 1.0f / sqrtf(var + 1e-5f);
#pragma unroll
    for (int g = 0; g < 8; ++g) {
      int g5 = (q << 3) + g;
      int d0 = g5 << 2;
      f32x4 cv = *(const f32x4*)&lds.C[(row << 7) + ((g5 ^ (row & 31)) << 2)];
      f32x4 bl = *(const f32x4*)(blin + d0);
      f32x4 gm = *(const f32x4*)(gam + d0);
      f32x4 bb = *(const f32x4*)(bet + d0);
      f32x4 o;
#pragma unroll
      for (int m = 0; m < 4; ++m) {
        float x = cv[m] + bl[m];
        float y = fmaxf((x - mean) * inv * gm[m] + bb[m], 0.f);
        uint32_t jj = ((uint32_t)n << 7) + (uint32_t)(d0 + m);
        o[m] = jax_keep(jj) ? (y * (1.0f / 0.9f)) : 0.0f;
      }
      *(f32x4*)(accout + ((size_t)n << 7) + d0) = o;
    }
  }
}

extern "C" void kernel_launch(void* const* d_in, const int* in_sizes, int n_in,
                              void* d_out, int out_size, void* d_ws, size_t ws_size,
                              hipStream_t stream) {
  (void)in_sizes; (void)n_in; (void)out_size; (void)ws_size;
  const float* hidden = (const float*)d_in[0];
  const int*   ei     = (const int*)d_in[1];
  const float* attr   = (const float*)d_in[2];
  const float* tim    = (const float*)d_in[3];
  const float* bnd    = (const float*)d_in[4];
  const float* Wmsg   = (const float*)d_in[5];
  const float* bmsg   = (const float*)d_in[6];
  const float* Wlin   = (const float*)d_in[7];
  const float* blin   = (const float*)d_in[8];
  const float* gam    = (const float*)d_in[9];
  const float* bet    = (const float*)d_in[10];

  float* acc = (float*)d_out;  // [N,128] f32 accumulator, finalized in-place

  char* ws = (char*)d_ws;
  u16*      Hp     = (u16*)(ws + 0);              // 12,800,000
  u16*      WhImg  = (u16*)(ws + 12800000);       //     32,768
  u16*      WcImg  = (u16*)(ws + 12832768);       //     16,384
  u16*      WlImg  = (u16*)(ws + 12849152);       //     32,768
  uint32_t* deg    = (uint32_t*)(ws + 12881920);  //    200,000
  uint32_t* cursor = (uint32_t*)(ws + 13081920);  //    200,000
  uint32_t* bsum   = (uint32_t*)(ws + 13281920);  //      1,024
  uint32_t* boff   = (uint32_t*)(ws + 13282944);  //      1,024
  uint32_t* ex     = (uint32_t*)(ws + 13283968);  //    200,000
  uint32_t* sd     = (uint32_t*)(ws + 13483968);  //  2,000,128 (NEPAD*4)
  int*      perm   = (int*)(ws + 15484096);       //  2,000,128 (NEPAD*4)
  // total 17,484,224 bytes

  hipMemsetAsync(deg, 0, (size_t)NN * 4, stream);
  hipMemsetAsync(acc, 0, (size_t)NN * 128 * 4, stream);

  k_prep <<<dim3(3), dim3(256), 0, stream>>>(Wmsg, Wlin, WhImg, WcImg, WlImg);
  k_hp   <<<dim3(NT_BLOCKS), dim3(256), 0, stream>>>(hidden, WhImg, bmsg, ei, deg, Hp);
  k_scan1<<<dim3(NBLK_N), dim3(256), 0, stream>>>(deg, ex, bsum);
  k_scan2<<<dim3(1), dim3(256), 0, stream>>>(bsum, boff);
  k_scan3<<<dim3(NBLK_N), dim3(256), 0, stream>>>(ex, boff, cursor);
  k_perm <<<dim3((NE + 255) / 256), dim3(256), 0, stream>>>(ei, cursor, perm, sd);
  k_edge3<<<dim3(NEPAD / SPB), dim3(256), 0, stream>>>(perm, sd, attr, tim, WcImg, Hp, acc);
  k_out  <<<dim3(NT_BLOCKS), dim3(256), 0, stream>>>(acc, bnd, WlImg, blin, gam, bet);
}

// Round 5
// 332.676 us; speedup vs baseline: 1.2917x; 1.0890x over previous
//
#include <hip/hip_runtime.h>
#include <stdint.h>

#define NN 50000
#define NE 500000
#define SPB 32
#define NEB (NE / SPB)                        // 15625 edge tiles, exact
#define NT_BLOCKS ((NN + 63) / 64)            // 782 (k_hp / k_out grids)
#define DEG_STRIDE (NT_BLOCKS * 256)          // 200192
#define NBLK_N ((NN + 255) / 256)             // 196

typedef short bf16x8 __attribute__((ext_vector_type(8)));
typedef float f32x4 __attribute__((ext_vector_type(4)));
typedef unsigned short u16;
typedef unsigned short u16x4 __attribute__((ext_vector_type(4)));
typedef unsigned short u16x8 __attribute__((ext_vector_type(8)));
typedef unsigned int u32x2 __attribute__((ext_vector_type(2)));
typedef unsigned int u32x4 __attribute__((ext_vector_type(4)));

__device__ __forceinline__ u16 f2b(float x) {
  uint32_t u = __builtin_bit_cast(uint32_t, x);
  return (u16)((u + 0x7fffu + ((u >> 16) & 1u)) >> 16);
}
__device__ __forceinline__ float b2f(uint32_t lo16) {
  return __builtin_bit_cast(float, lo16 << 16);
}

// JAX threefry2x32, key = jax.random.key(42) -> (0, 42)
__device__ __forceinline__ void threefry(uint32_t x0, uint32_t x1,
                                         uint32_t& o0, uint32_t& o1) {
  const uint32_t k0 = 0u, k1 = 42u, k2 = 0u ^ 42u ^ 0x1BD11BDAu;
  x0 += k0; x1 += k1;
#define TFR(r) { x0 += x1; x1 = (x1 << r) | (x1 >> (32 - r)); x1 ^= x0; }
  TFR(13) TFR(15) TFR(26) TFR(6)
  x0 += k1; x1 += k2 + 1u;
  TFR(17) TFR(29) TFR(16) TFR(24)
  x0 += k2; x1 += k0 + 2u;
  TFR(13) TFR(15) TFR(26) TFR(6)
  x0 += k0; x1 += k1 + 3u;
  TFR(17) TFR(29) TFR(16) TFR(24)
  x0 += k1; x1 += k2 + 4u;
  TFR(13) TFR(15) TFR(26) TFR(6)
  x0 += k2; x1 += k0 + 5u;
#undef TFR
  o0 = x0; o1 = x1;
}

__device__ __forceinline__ bool jax_keep(uint32_t j) {
  uint32_t o0, o1;
  threefry(0u, j, o0, o1);
  uint32_t bits = o0 ^ o1;
  float u = __builtin_bit_cast(float, (bits >> 9) | 0x3f800000u) - 1.0f;
  return u < 0.9f;
}

// ---- weight images + deg zeroing (fused memset saves a dispatch)
__global__ __launch_bounds__(256) void k_prep(const float* __restrict__ Wmsg,
                                              const float* __restrict__ Wlin,
                                              u16* __restrict__ WhImg,
                                              u16* __restrict__ WcImg,
                                              u16* __restrict__ WlImg,
                                              uint32_t* __restrict__ deg) {
  const int t = threadIdx.x, b = blockIdx.x;
  if (b == 0) {
#pragma unroll
    for (int it = 0; it < 16; ++it) {
      int g = t + (it << 8);
      int d = g >> 5, k4 = (g & 31) << 2;
      u16x4 v = {f2b(Wmsg[(k4 + 0) * 128 + d]), f2b(Wmsg[(k4 + 1) * 128 + d]),
                 f2b(Wmsg[(k4 + 2) * 128 + d]), f2b(Wmsg[(k4 + 3) * 128 + d])};
      *(u16x4*)&WhImg[(d << 7) + k4] = v;
    }
  } else if (b == 1) {
#pragma unroll
    for (int it = 0; it < 8; ++it) {
      int g = t + (it << 8);
      int d = g >> 4, k4 = (g & 15) << 2;
      u16x4 v = {f2b(Wmsg[(128 + k4 + 0) * 128 + d]), f2b(Wmsg[(128 + k4 + 1) * 128 + d]),
                 f2b(Wmsg[(128 + k4 + 2) * 128 + d]), f2b(Wmsg[(128 + k4 + 3) * 128 + d])};
      *(u16x4*)&WcImg[(d << 6) + k4] = v;
    }
  } else if (b == 2) {
#pragma unroll
    for (int it = 0; it < 16; ++it) {
      int g = t + (it << 8);
      int d = g >> 5, k4 = (g & 31) << 2;
      u16x4 v = {f2b(Wlin[(k4 + 0) * 128 + d]), f2b(Wlin[(k4 + 1) * 128 + d]),
                 f2b(Wlin[(k4 + 2) * 128 + d]), f2b(Wlin[(k4 + 3) * 128 + d])};
      *(u16x4*)&WlImg[(d << 7) + k4] = v;
    }
  } else {
    for (int i = ((b - 3) << 8) + t; i < NN; i += 13 * 256) deg[i] = 0u;
  }
}

// ---- scan stage 1: per-256-block exclusive scan + block sums
__global__ __launch_bounds__(256) void k_scan1(const uint32_t* __restrict__ deg,
                                               uint32_t* __restrict__ ex,
                                               uint32_t* __restrict__ bsum) {
  __shared__ uint32_t s[256];
  int t = threadIdx.x;
  int i = blockIdx.x * 256 + t;
  uint32_t v = (i < NN) ? deg[i] : 0u;
  s[t] = v;
  __syncthreads();
#pragma unroll
  for (int off = 1; off < 256; off <<= 1) {
    uint32_t y = (t >= off) ? s[t - off] : 0u;
    __syncthreads();
    s[t] += y;
    __syncthreads();
  }
  if (i < NN) ex[i] = s[t] - v;
  if (t == 255) bsum[blockIdx.x] = s[255];
}

// ---- scan stages 2+3 merged: each block redundantly scans the tiny bsum
// array, then finalizes cursor for its 256 nodes.
__global__ __launch_bounds__(256) void k_scan23(const uint32_t* __restrict__ bsum,
                                                const uint32_t* __restrict__ ex,
                                                uint32_t* __restrict__ cursor) {
  __shared__ uint32_t s[256];
  int t = threadIdx.x;
  uint32_t v = (t < NBLK_N) ? bsum[t] : 0u;
  s[t] = v;
  __syncthreads();
#pragma unroll
  for (int off = 1; off < 256; off <<= 1) {
    uint32_t y = (t >= off) ? s[t - off] : 0u;
    __syncthreads();
    s[t] += y;
    __syncthreads();
  }
  const uint32_t boff = s[blockIdx.x] - bsum[blockIdx.x];  // exclusive prefix
  int i = blockIdx.x * 256 + t;
  if (i < NN) cursor[i] = ex[i] + boff;
}

// k_perm: index-only scatter, single packed 8B write per edge.
// psd[pos] = {e, src|(dst<<16)}
__global__ __launch_bounds__(256) void k_perm(const int* __restrict__ ei,
                                              uint32_t* __restrict__ cursor,
                                              u32x2* __restrict__ psd) {
  int i = blockIdx.x * 256 + threadIdx.x;
  if (i < NE) {
    uint32_t s = (uint32_t)ei[i], d = (uint32_t)ei[NE + i];
    uint32_t pos = atomicAdd(&cursor[d], 1u);
    u32x2 pv = {(uint32_t)i, s | (d << 16)};
    psd[pos] = pv;
  }
}

// K2: SPB=32 edges/block (no tail: NE%32==0), LDS 16 KB union -> 8 blocks/CU
// (wave-capped). A gathered from attr/tim f32, bf16-converted in-kernel.
__global__ __launch_bounds__(256, 8) void k_edge3(const u32x2* __restrict__ psd,
                                                  const float* __restrict__ attr,
                                                  const float* __restrict__ tim,
                                                  const u16* __restrict__ WcImg,
                                                  const u16* __restrict__ Hp,
                                                  float* __restrict__ acc) {
  __shared__ union { u16 A[32 * 64]; float C[32 * 128]; } lds;  // 16 KB
  __shared__ int sdst[32];
  const int t = threadIdx.x;
  const long e0 = (long)blockIdx.x << 5;

  // stage: 8 threads/row. Each loads its row's {e, src|dst} (broadcast line),
  // gathers 32 B of f32 features, converts to bf16, swizzle-stores to LDS,
  // and prefetches its 16-col slice of Hp[src] for the relu stage.
  const int row = t >> 3, g = t & 7;
  const u32x2 pv = psd[e0 + row];
  const int e = (int)pv.x;
  const int src = (int)(pv.y & 0xffffu);
  const float* src8 = (g < 4) ? (attr + ((size_t)e << 5) + (g << 3))
                              : (tim + ((size_t)e << 5) + ((g - 4) << 3));
  f32x4 v0 = *(const f32x4*)src8;
  f32x4 v1 = *(const f32x4*)(src8 + 4);
  u16x8 bb = {f2b(v0[0]), f2b(v0[1]), f2b(v0[2]), f2b(v0[3]),
              f2b(v1[0]), f2b(v1[1]), f2b(v1[2]), f2b(v1[3])};
  *(u16x8*)&lds.A[(row << 6) + ((g ^ (row & 7)) << 3)] = bb;
  // Hp[src][g*16 .. g*16+15] (32 B)
  const u32x4 hpA = *(const u32x4*)(Hp + ((size_t)src << 7) + (g << 4));
  const u32x4 hpB = *(const u32x4*)(Hp + ((size_t)src << 7) + (g << 4) + 8);
  if (g == 0) sdst[row] = (int)(pv.y >> 16);
  __syncthreads();

  const int lane = t & 63, w = t >> 6;
  const int quad = lane >> 4, lr = lane & 15;
  f32x4 c[2][2];
#pragma unroll
  for (int i = 0; i < 2; ++i)
#pragma unroll
    for (int j = 0; j < 2; ++j) { f32x4 z = {0.f, 0.f, 0.f, 0.f}; c[i][j] = z; }
#pragma unroll
  for (int ks = 0; ks < 64; ks += 32) {
    const int gi = (ks >> 3) + quad;
    bf16x8 a[2], b[2];
#pragma unroll
    for (int i = 0; i < 2; ++i) {
      int r2 = (i << 4) + lr;
      a[i] = *(const bf16x8*)&lds.A[(r2 << 6) + ((gi ^ (r2 & 7)) << 3)];
    }
#pragma unroll
    for (int j = 0; j < 2; ++j) {
      int col = (w << 5) + (j << 4) + lr;
      b[j] = *(const bf16x8*)&WcImg[(col << 6) + (gi << 3)];
    }
#pragma unroll
    for (int i = 0; i < 2; ++i)
#pragma unroll
      for (int j = 0; j < 2; ++j)
        c[i][j] = __builtin_amdgcn_mfma_f32_16x16x32_bf16(a[i], b[j], c[i][j], 0, 0, 0);
  }
  __syncthreads();  // A consumed; C may overwrite
#pragma unroll
  for (int i = 0; i < 2; ++i)
#pragma unroll
    for (int j = 0; j < 2; ++j)
#pragma unroll
      for (int r = 0; r < 4; ++r) {
        int rr = (i << 4) + (quad << 2) + r;
        int col = (w << 5) + (j << 4) + lr;
        lds.C[(rr << 7) + ((((col >> 2) ^ rr) << 2) + (col & 3))] = c[i][j][r];
      }
  __syncthreads();
  // stage 1: msg = relu(P + Hp[src]); thread (row,g) owns cols g*16..+15
  {
#pragma unroll
    for (int gg = 0; gg < 4; ++gg) {
      int cb4 = (g << 2) + gg;  // col/4
      float* p = &lds.C[(row << 7) + ((cb4 ^ row) << 2)];
      f32x4 cv = *(const f32x4*)p;
      const u32x4 hw = (gg < 2) ? hpA : hpB;
      const int k = (gg & 1) << 1;
      uint32_t w0 = hw[k], w1 = hw[k + 1];
      cv[0] = fmaxf(cv[0] + b2f(w0 & 0xffffu), 0.f);
      cv[1] = fmaxf(cv[1] + b2f(w0 >> 16), 0.f);
      cv[2] = fmaxf(cv[2] + b2f(w1 & 0xffffu), 0.f);
      cv[3] = fmaxf(cv[3] + b2f(w1 >> 16), 0.f);
      *(f32x4*)p = cv;
    }
  }
  __syncthreads();
  // stage 2: segmented reduction, 2 halves x 16 slots, 128 cols
  {
    const int col = t & 127, half = t >> 7;
    const int beg = half << 4, end = beg + 16;
    int cur = sdst[beg];
    float sum = 0.f;
    int runstart = beg;
    for (int ss = beg; ss < end; ++ss) {
      int d = sdst[ss];
      if (d != cur) {
        if (cur >= 0) {
          float* p = acc + ((size_t)cur << 7) + col;
          if (runstart == beg) unsafeAtomicAdd(p, sum);
          else *p = sum;
        }
        cur = d; sum = 0.f; runstart = ss;
      }
      sum += lds.C[(ss << 7) + ((((col >> 2) ^ ss) << 2) + (col & 3))];
    }
    if (cur >= 0) unsafeAtomicAdd(acc + ((size_t)cur << 7) + col, sum);
  }
}

// K1: Hp = bf16(hidden @ W_msg[0:128,:] + b_msg). Fused deg count + acc zero.
__global__ __launch_bounds__(256) void k_hp(const float* __restrict__ hidden,
                                            const u16* __restrict__ WhImg,
                                            const float* __restrict__ bmsg,
                                            const int* __restrict__ ei,
                                            uint32_t* __restrict__ deg,
                                            u16* __restrict__ Hp,
                                            float* __restrict__ acc) {
  __shared__ u16 sA[64 * 128];
  const int t = threadIdx.x;
  const int row0 = blockIdx.x << 6;
  // fused: zero acc (replaces a memset dispatch)
  {
    f32x4* acc4 = (f32x4*)acc;
    const f32x4 z = {0.f, 0.f, 0.f, 0.f};
    for (int i = blockIdx.x * 256 + t; i < NN * 32; i += DEG_STRIDE) acc4[i] = z;
  }
  for (int i = blockIdx.x * 256 + t; i < NE; i += DEG_STRIDE)
    atomicAdd(&deg[ei[NE + i]], 1u);
#pragma unroll
  for (int it = 0; it < 8; ++it) {
    int li = t + (it << 8);
    int row = li >> 5, c4 = li & 31;
    int n = row0 + row;
    f32x4 v = {0.f, 0.f, 0.f, 0.f};
    if (n < NN) v = *(const f32x4*)(hidden + ((size_t)n << 7) + (c4 << 2));
    u16x4 b = {f2b(v[0]), f2b(v[1]), f2b(v[2]), f2b(v[3])};
    *(u16x4*)&sA[(row << 7) + ((((c4 >> 1) ^ (row & 15)) << 3) + ((c4 & 1) << 2))] = b;
  }
  __syncthreads();
  const int lane = t & 63, w = t >> 6;
  const int quad = lane >> 4, lr = lane & 15;
  f32x4 c[4][2];
#pragma unroll
  for (int i = 0; i < 4; ++i)
#pragma unroll
    for (int j = 0; j < 2; ++j) { f32x4 z = {0.f, 0.f, 0.f, 0.f}; c[i][j] = z; }
#pragma unroll
  for (int ks = 0; ks < 128; ks += 32) {
    const int gi = (ks >> 3) + quad;
    bf16x8 a[4], b[2];
#pragma unroll
    for (int i = 0; i < 4; ++i) {
      int row = (i << 4) + lr;
      a[i] = *(const bf16x8*)&sA[(row << 7) + ((gi ^ (row & 15)) << 3)];
    }
#pragma unroll
    for (int j = 0; j < 2; ++j) {
      int col = (w << 5) + (j << 4) + lr;
      b[j] = *(const bf16x8*)&WhImg[(col << 7) + (gi << 3)];
    }
#pragma unroll
    for (int i = 0; i < 4; ++i)
#pragma unroll
      for (int j = 0; j < 2; ++j)
        c[i][j] = __builtin_amdgcn_mfma_f32_16x16x32_bf16(a[i], b[j], c[i][j], 0, 0, 0);
  }
#pragma unroll
  for (int j = 0; j < 2; ++j) {
    int d = (w << 5) + (j << 4) + lr;
    float bias = bmsg[d];
#pragma unroll
    for (int i = 0; i < 4; ++i) {
      int nb = row0 + (i << 4) + (quad << 2);
#pragma unroll
      for (int r = 0; r < 4; ++r) {
        int n = nb + r;
        if (n < NN) Hp[((size_t)n << 7) + d] = f2b(c[i][j][r] + bias);
      }
    }
  }
}

// K3 (in-place): out = dropout(relu(LN((acc+boundary) @ W_lin + b_lin)))
__global__ __launch_bounds__(256) void k_out(float* accout,
                                             const float* __restrict__ bnd,
                                             const u16* __restrict__ WlImg,
                                             const float* __restrict__ blin,
                                             const float* __restrict__ gam,
                                             const float* __restrict__ bet) {
  __shared__ union { u16 A[64 * 128]; float C[64 * 128]; } lds;  // 32 KB
  const int t = threadIdx.x;
  const int row0 = blockIdx.x << 6;
#pragma unroll
  for (int it = 0; it < 8; ++it) {
    int li = t + (it << 8);
    int row = li >> 5, c4 = li & 31;
    int n = row0 + row;
    f32x4 v = {0.f, 0.f, 0.f, 0.f};
    if (n < NN) {
      f32x4 a = *(const f32x4*)(accout + ((size_t)n << 7) + (c4 << 2));
      f32x4 b = *(const f32x4*)(bnd + ((size_t)n << 7) + (c4 << 2));
      v = a + b;
    }
    u16x4 bb = {f2b(v[0]), f2b(v[1]), f2b(v[2]), f2b(v[3])};
    *(u16x4*)&lds.A[(row << 7) + ((((c4 >> 1) ^ (row & 15)) << 3) + ((c4 & 1) << 2))] = bb;
  }
  __syncthreads();
  const int lane = t & 63, w = t >> 6;
  const int quad = lane >> 4, lr = lane & 15;
  f32x4 c[4][2];
#pragma unroll
  for (int i = 0; i < 4; ++i)
#pragma unroll
    for (int j = 0; j < 2; ++j) { f32x4 z = {0.f, 0.f, 0.f, 0.f}; c[i][j] = z; }
#pragma unroll
  for (int ks = 0; ks < 128; ks += 32) {
    const int gi = (ks >> 3) + quad;
    bf16x8 a[4], b[2];
#pragma unroll
    for (int i = 0; i < 4; ++i) {
      int row = (i << 4) + lr;
      a[i] = *(const bf16x8*)&lds.A[(row << 7) + ((gi ^ (row & 15)) << 3)];
    }
#pragma unroll
    for (int j = 0; j < 2; ++j) {
      int col = (w << 5) + (j << 4) + lr;
      b[j] = *(const bf16x8*)&WlImg[(col << 7) + (gi << 3)];
    }
#pragma unroll
    for (int i = 0; i < 4; ++i)
#pragma unroll
      for (int j = 0; j < 2; ++j)
        c[i][j] = __builtin_amdgcn_mfma_f32_16x16x32_bf16(a[i], b[j], c[i][j], 0, 0, 0);
  }
  __syncthreads();  // all waves done reading A before C overwrites
#pragma unroll
  for (int i = 0; i < 4; ++i)
#pragma unroll
    for (int j = 0; j < 2; ++j)
#pragma unroll
      for (int r = 0; r < 4; ++r) {
        int row = (i << 4) + (quad << 2) + r;
        int col = (w << 5) + (j << 4) + lr;
        lds.C[(row << 7) + ((((col >> 2) ^ (row & 31)) << 2) + (col & 3))] = c[i][j][r];
      }
  __syncthreads();
  // LN + relu + dropout: 4 threads/row, thread q owns cols q*32..+31
  const int row = t >> 2, q = t & 3;
  const int n = row0 + row;
  float s1 = 0.f, s2 = 0.f;
  if (n < NN) {
#pragma unroll
    for (int g = 0; g < 8; ++g) {
      int g5 = (q << 3) + g;
      f32x4 cv = *(const f32x4*)&lds.C[(row << 7) + ((g5 ^ (row & 31)) << 2)];
      f32x4 bl = *(const f32x4*)(blin + (g5 << 2));
#pragma unroll
      for (int m = 0; m < 4; ++m) {
        float x = cv[m] + bl[m];
        s1 += x; s2 += x * x;
      }
    }
  }
  s1 += __shfl_xor(s1, 1, 64); s1 += __shfl_xor(s1, 2, 64);
  s2 += __shfl_xor(s2, 1, 64); s2 += __shfl_xor(s2, 2, 64);
  if (n < NN) {
    const float mean = s1 * 0.0078125f;
    const float var = s2 * 0.0078125f - mean * mean;
    const float inv = 1.0f / sqrtf(var + 1e-5f);
#pragma unroll
    for (int g = 0; g < 8; ++g) {
      int g5 = (q << 3) + g;
      int d0 = g5 << 2;
      f32x4 cv = *(const f32x4*)&lds.C[(row << 7) + ((g5 ^ (row & 31)) << 2)];
      f32x4 bl = *(const f32x4*)(blin + d0);
      f32x4 gm = *(const f32x4*)(gam + d0);
      f32x4 bb = *(const f32x4*)(bet + d0);
      f32x4 o;
#pragma unroll
      for (int m = 0; m < 4; ++m) {
        float x = cv[m] + bl[m];
        float y = fmaxf((x - mean) * inv * gm[m] + bb[m], 0.f);
        uint32_t jj = ((uint32_t)n << 7) + (uint32_t)(d0 + m);
        o[m] = jax_keep(jj) ? (y * (1.0f / 0.9f)) : 0.0f;
      }
      *(f32x4*)(accout + ((size_t)n << 7) + d0) = o;
    }
  }
}

extern "C" void kernel_launch(void* const* d_in, const int* in_sizes, int n_in,
                              void* d_out, int out_size, void* d_ws, size_t ws_size,
                              hipStream_t stream) {
  (void)in_sizes; (void)n_in; (void)out_size; (void)ws_size;
  const float* hidden = (const float*)d_in[0];
  const int*   ei     = (const int*)d_in[1];
  const float* attr   = (const float*)d_in[2];
  const float* tim    = (const float*)d_in[3];
  const float* bnd    = (const float*)d_in[4];
  const float* Wmsg   = (const float*)d_in[5];
  const float* bmsg   = (const float*)d_in[6];
  const float* Wlin   = (const float*)d_in[7];
  const float* blin   = (const float*)d_in[8];
  const float* gam    = (const float*)d_in[9];
  const float* bet    = (const float*)d_in[10];

  float* acc = (float*)d_out;  // [N,128] f32 accumulator, finalized in-place

  char* ws = (char*)d_ws;
  u16*      Hp     = (u16*)(ws + 0);              // 12,800,000
  u16*      WhImg  = (u16*)(ws + 12800000);       //     32,768
  u16*      WcImg  = (u16*)(ws + 12832768);       //     16,384
  u16*      WlImg  = (u16*)(ws + 12849152);       //     32,768
  uint32_t* deg    = (uint32_t*)(ws + 12881920);  //    200,000
  uint32_t* cursor = (uint32_t*)(ws + 13081920);  //    200,000
  uint32_t* bsum   = (uint32_t*)(ws + 13281920);  //      1,024
  uint32_t* ex     = (uint32_t*)(ws + 13282944);  //    200,000
  u32x2*    psd    = (u32x2*)(ws + 13482944);     //  4,000,000 (NE*8)
  // total 17,482,944 bytes

  k_prep  <<<dim3(16), dim3(256), 0, stream>>>(Wmsg, Wlin, WhImg, WcImg, WlImg, deg);
  k_hp    <<<dim3(NT_BLOCKS), dim3(256), 0, stream>>>(hidden, WhImg, bmsg, ei, deg, Hp, acc);
  k_scan1 <<<dim3(NBLK_N), dim3(256), 0, stream>>>(deg, ex, bsum);
  k_scan23<<<dim3(NBLK_N), dim3(256), 0, stream>>>(bsum, ex, cursor);
  k_perm  <<<dim3((NE + 255) / 256), dim3(256), 0, stream>>>(ei, cursor, psd);
  k_edge3 <<<dim3(NEB), dim3(256), 0, stream>>>(psd, attr, tim, WcImg, Hp, acc);
  k_out   <<<dim3(NT_BLOCKS), dim3(256), 0, stream>>>(acc, bnd, WlImg, blin, gam, bet);
}

// Round 6
// 330.205 us; speedup vs baseline: 1.3013x; 1.0075x over previous
//
#include <hip/hip_runtime.h>
#include <stdint.h>

#define NN 50000
#define NE 500000
#define SPB 32
#define NEB (NE / SPB)                        // 15625 edge tiles, exact
#define NT16 3125                             // NN/16 exactly (k_hp / k_out grids)
#define ST16 (NT16 * 256)                     // 800000 grid-stride
#define NBLK_N ((NN + 255) / 256)             // 196

typedef short bf16x8 __attribute__((ext_vector_type(8)));
typedef float f32x4 __attribute__((ext_vector_type(4)));
typedef unsigned short u16;
typedef unsigned short u16x4 __attribute__((ext_vector_type(4)));
typedef unsigned short u16x8 __attribute__((ext_vector_type(8)));
typedef unsigned int u32x2 __attribute__((ext_vector_type(2)));
typedef unsigned int u32x4 __attribute__((ext_vector_type(4)));

__device__ __forceinline__ u16 f2b(float x) {
  uint32_t u = __builtin_bit_cast(uint32_t, x);
  return (u16)((u + 0x7fffu + ((u >> 16) & 1u)) >> 16);
}
__device__ __forceinline__ float b2f(uint32_t lo16) {
  return __builtin_bit_cast(float, lo16 << 16);
}

// JAX threefry2x32, key = jax.random.key(42) -> (0, 42)
__device__ __forceinline__ void threefry(uint32_t x0, uint32_t x1,
                                         uint32_t& o0, uint32_t& o1) {
  const uint32_t k0 = 0u, k1 = 42u, k2 = 0u ^ 42u ^ 0x1BD11BDAu;
  x0 += k0; x1 += k1;
#define TFR(r) { x0 += x1; x1 = (x1 << r) | (x1 >> (32 - r)); x1 ^= x0; }
  TFR(13) TFR(15) TFR(26) TFR(6)
  x0 += k1; x1 += k2 + 1u;
  TFR(17) TFR(29) TFR(16) TFR(24)
  x0 += k2; x1 += k0 + 2u;
  TFR(13) TFR(15) TFR(26) TFR(6)
  x0 += k0; x1 += k1 + 3u;
  TFR(17) TFR(29) TFR(16) TFR(24)
  x0 += k1; x1 += k2 + 4u;
  TFR(13) TFR(15) TFR(26) TFR(6)
  x0 += k2; x1 += k0 + 5u;
#undef TFR
  o0 = x0; o1 = x1;
}

__device__ __forceinline__ bool jax_keep(uint32_t j) {
  uint32_t o0, o1;
  threefry(0u, j, o0, o1);
  uint32_t bits = o0 ^ o1;
  float u = __builtin_bit_cast(float, (bits >> 9) | 0x3f800000u) - 1.0f;
  return u < 0.9f;
}

// ---- weight images + deg zeroing (fused memset saves a dispatch)
__global__ __launch_bounds__(256) void k_prep(const float* __restrict__ Wmsg,
                                              const float* __restrict__ Wlin,
                                              u16* __restrict__ WhImg,
                                              u16* __restrict__ WcImg,
                                              u16* __restrict__ WlImg,
                                              uint32_t* __restrict__ deg) {
  const int t = threadIdx.x, b = blockIdx.x;
  if (b == 0) {
#pragma unroll
    for (int it = 0; it < 16; ++it) {
      int g = t + (it << 8);
      int d = g >> 5, k4 = (g & 31) << 2;
      u16x4 v = {f2b(Wmsg[(k4 + 0) * 128 + d]), f2b(Wmsg[(k4 + 1) * 128 + d]),
                 f2b(Wmsg[(k4 + 2) * 128 + d]), f2b(Wmsg[(k4 + 3) * 128 + d])};
      *(u16x4*)&WhImg[(d << 7) + k4] = v;
    }
  } else if (b == 1) {
#pragma unroll
    for (int it = 0; it < 8; ++it) {
      int g = t + (it << 8);
      int d = g >> 4, k4 = (g & 15) << 2;
      u16x4 v = {f2b(Wmsg[(128 + k4 + 0) * 128 + d]), f2b(Wmsg[(128 + k4 + 1) * 128 + d]),
                 f2b(Wmsg[(128 + k4 + 2) * 128 + d]), f2b(Wmsg[(128 + k4 + 3) * 128 + d])};
      *(u16x4*)&WcImg[(d << 6) + k4] = v;
    }
  } else if (b == 2) {
#pragma unroll
    for (int it = 0; it < 16; ++it) {
      int g = t + (it << 8);
      int d = g >> 5, k4 = (g & 31) << 2;
      u16x4 v = {f2b(Wlin[(k4 + 0) * 128 + d]), f2b(Wlin[(k4 + 1) * 128 + d]),
                 f2b(Wlin[(k4 + 2) * 128 + d]), f2b(Wlin[(k4 + 3) * 128 + d])};
      *(u16x4*)&WlImg[(d << 7) + k4] = v;
    }
  } else {
    for (int i = ((b - 3) << 8) + t; i < NN; i += 13 * 256) deg[i] = 0u;
  }
}

// ---- scan stage 1: per-256-block exclusive scan + block sums
__global__ __launch_bounds__(256) void k_scan1(const uint32_t* __restrict__ deg,
                                               uint32_t* __restrict__ ex,
                                               uint32_t* __restrict__ bsum) {
  __shared__ uint32_t s[256];
  int t = threadIdx.x;
  int i = blockIdx.x * 256 + t;
  uint32_t v = (i < NN) ? deg[i] : 0u;
  s[t] = v;
  __syncthreads();
#pragma unroll
  for (int off = 1; off < 256; off <<= 1) {
    uint32_t y = (t >= off) ? s[t - off] : 0u;
    __syncthreads();
    s[t] += y;
    __syncthreads();
  }
  if (i < NN) ex[i] = s[t] - v;
  if (t == 255) bsum[blockIdx.x] = s[255];
}

// ---- scan stages 2+3 merged
__global__ __launch_bounds__(256) void k_scan23(const uint32_t* __restrict__ bsum,
                                                const uint32_t* __restrict__ ex,
                                                uint32_t* __restrict__ cursor) {
  __shared__ uint32_t s[256];
  int t = threadIdx.x;
  uint32_t v = (t < NBLK_N) ? bsum[t] : 0u;
  s[t] = v;
  __syncthreads();
#pragma unroll
  for (int off = 1; off < 256; off <<= 1) {
    uint32_t y = (t >= off) ? s[t - off] : 0u;
    __syncthreads();
    s[t] += y;
    __syncthreads();
  }
  const uint32_t boff = s[blockIdx.x] - bsum[blockIdx.x];  // exclusive prefix
  int i = blockIdx.x * 256 + t;
  if (i < NN) cursor[i] = ex[i] + boff;
}

// k_perm: index-only scatter, single packed 8B write per edge.
__global__ __launch_bounds__(256) void k_perm(const int* __restrict__ ei,
                                              uint32_t* __restrict__ cursor,
                                              u32x2* __restrict__ psd) {
  int i = blockIdx.x * 256 + threadIdx.x;
  if (i < NE) {
    uint32_t s = (uint32_t)ei[i], d = (uint32_t)ei[NE + i];
    uint32_t pos = atomicAdd(&cursor[d], 1u);
    u32x2 pv = {(uint32_t)i, s | (d << 16)};
    psd[pos] = pv;
  }
}

// K2: SPB=32 edges/block, LDS 16 KB union -> 8 blocks/CU (wave-capped).
__global__ __launch_bounds__(256, 8) void k_edge3(const u32x2* __restrict__ psd,
                                                  const float* __restrict__ attr,
                                                  const float* __restrict__ tim,
                                                  const u16* __restrict__ WcImg,
                                                  const u16* __restrict__ Hp,
                                                  float* __restrict__ acc) {
  __shared__ union { u16 A[32 * 64]; float C[32 * 128]; } lds;  // 16 KB
  __shared__ int sdst[32];
  const int t = threadIdx.x;
  const long e0 = (long)blockIdx.x << 5;

  const int row = t >> 3, g = t & 7;
  const u32x2 pv = psd[e0 + row];
  const int e = (int)pv.x;
  const int src = (int)(pv.y & 0xffffu);
  const float* src8 = (g < 4) ? (attr + ((size_t)e << 5) + (g << 3))
                              : (tim + ((size_t)e << 5) + ((g - 4) << 3));
  f32x4 v0 = *(const f32x4*)src8;
  f32x4 v1 = *(const f32x4*)(src8 + 4);
  u16x8 bb = {f2b(v0[0]), f2b(v0[1]), f2b(v0[2]), f2b(v0[3]),
              f2b(v1[0]), f2b(v1[1]), f2b(v1[2]), f2b(v1[3])};
  *(u16x8*)&lds.A[(row << 6) + ((g ^ (row & 7)) << 3)] = bb;
  const u32x4 hpA = *(const u32x4*)(Hp + ((size_t)src << 7) + (g << 4));
  const u32x4 hpB = *(const u32x4*)(Hp + ((size_t)src << 7) + (g << 4) + 8);
  if (g == 0) sdst[row] = (int)(pv.y >> 16);
  __syncthreads();

  const int lane = t & 63, w = t >> 6;
  const int quad = lane >> 4, lr = lane & 15;
  f32x4 c[2][2];
#pragma unroll
  for (int i = 0; i < 2; ++i)
#pragma unroll
    for (int j = 0; j < 2; ++j) { f32x4 z = {0.f, 0.f, 0.f, 0.f}; c[i][j] = z; }
#pragma unroll
  for (int ks = 0; ks < 64; ks += 32) {
    const int gi = (ks >> 3) + quad;
    bf16x8 a[2], b[2];
#pragma unroll
    for (int i = 0; i < 2; ++i) {
      int r2 = (i << 4) + lr;
      a[i] = *(const bf16x8*)&lds.A[(r2 << 6) + ((gi ^ (r2 & 7)) << 3)];
    }
#pragma unroll
    for (int j = 0; j < 2; ++j) {
      int col = (w << 5) + (j << 4) + lr;
      b[j] = *(const bf16x8*)&WcImg[(col << 6) + (gi << 3)];
    }
#pragma unroll
    for (int i = 0; i < 2; ++i)
#pragma unroll
      for (int j = 0; j < 2; ++j)
        c[i][j] = __builtin_amdgcn_mfma_f32_16x16x32_bf16(a[i], b[j], c[i][j], 0, 0, 0);
  }
  __syncthreads();  // A consumed; C may overwrite
#pragma unroll
  for (int i = 0; i < 2; ++i)
#pragma unroll
    for (int j = 0; j < 2; ++j)
#pragma unroll
      for (int r = 0; r < 4; ++r) {
        int rr = (i << 4) + (quad << 2) + r;
        int col = (w << 5) + (j << 4) + lr;
        lds.C[(rr << 7) + ((((col >> 2) ^ rr) << 2) + (col & 3))] = c[i][j][r];
      }
  __syncthreads();
  // stage 1: msg = relu(P + Hp[src]); thread (row,g) owns cols g*16..+15
  {
#pragma unroll
    for (int gg = 0; gg < 4; ++gg) {
      int cb4 = (g << 2) + gg;  // col/4
      float* p = &lds.C[(row << 7) + ((cb4 ^ row) << 2)];
      f32x4 cv = *(const f32x4*)p;
      const u32x4 hw = (gg < 2) ? hpA : hpB;
      const int k = (gg & 1) << 1;
      uint32_t w0 = hw[k], w1 = hw[k + 1];
      cv[0] = fmaxf(cv[0] + b2f(w0 & 0xffffu), 0.f);
      cv[1] = fmaxf(cv[1] + b2f(w0 >> 16), 0.f);
      cv[2] = fmaxf(cv[2] + b2f(w1 & 0xffffu), 0.f);
      cv[3] = fmaxf(cv[3] + b2f(w1 >> 16), 0.f);
      *(f32x4*)p = cv;
    }
  }
  __syncthreads();
  // stage 2: segmented reduction, 2 halves x 16 slots, 128 cols
  {
    const int col = t & 127, half = t >> 7;
    const int beg = half << 4, end = beg + 16;
    int cur = sdst[beg];
    float sum = 0.f;
    int runstart = beg;
    for (int ss = beg; ss < end; ++ss) {
      int d = sdst[ss];
      if (d != cur) {
        if (cur >= 0) {
          float* p = acc + ((size_t)cur << 7) + col;
          if (runstart == beg) unsafeAtomicAdd(p, sum);
          else *p = sum;
        }
        cur = d; sum = 0.f; runstart = ss;
      }
      sum += lds.C[(ss << 7) + ((((col >> 2) ^ ss) << 2) + (col & 3))];
    }
    if (cur >= 0) unsafeAtomicAdd(acc + ((size_t)cur << 7) + col, sum);
  }
}

// K1: Hp = bf16(hidden @ W_msg[0:128,:] + b_msg). 16-row tiles (3125 blocks,
// ~8 blocks/CU), coalesced u16x8 Hp stores via LDS repack. Fused deg + acc0.
__global__ __launch_bounds__(256) void k_hp(const float* __restrict__ hidden,
                                            const u16* __restrict__ WhImg,
                                            const float* __restrict__ bmsg,
                                            const int* __restrict__ ei,
                                            uint32_t* __restrict__ deg,
                                            u16* __restrict__ Hp,
                                            float* __restrict__ acc) {
  __shared__ union { u16 A[16 * 128]; float C[16 * 128]; } lds;  // 8 KB
  const int t = threadIdx.x;
  const int row0 = blockIdx.x << 4;
  // fused: zero acc (NN*32 f32x4 = 1.6M; 2 iters/thread)
  {
    f32x4* acc4 = (f32x4*)acc;
    const f32x4 z = {0.f, 0.f, 0.f, 0.f};
    for (int i = blockIdx.x * 256 + t; i < NN * 32; i += ST16) acc4[i] = z;
  }
  // fused: deg count (1 edge/thread, fire-and-forget atomic)
  {
    int i = blockIdx.x * 256 + t;
    if (i < NE) atomicAdd(&deg[ei[NE + i]], 1u);
  }
  const int srow = t >> 4, sq = t & 15;  // 16 threads/row, 8 cols each
  {
    const float* hp8 = hidden + ((size_t)(row0 + srow) << 7) + (sq << 3);
    f32x4 v0 = *(const f32x4*)hp8;
    f32x4 v1 = *(const f32x4*)(hp8 + 4);
    u16x8 b = {f2b(v0[0]), f2b(v0[1]), f2b(v0[2]), f2b(v0[3]),
               f2b(v1[0]), f2b(v1[1]), f2b(v1[2]), f2b(v1[3])};
    *(u16x8*)&lds.A[(srow << 7) + ((sq ^ srow) << 3)] = b;
  }
  __syncthreads();
  const int lane = t & 63, w = t >> 6;
  const int quad = lane >> 4, lr = lane & 15;
  f32x4 c[2];
#pragma unroll
  for (int j = 0; j < 2; ++j) { f32x4 z = {0.f, 0.f, 0.f, 0.f}; c[j] = z; }
#pragma unroll
  for (int ks = 0; ks < 128; ks += 32) {
    const int gi = (ks >> 3) + quad;
    bf16x8 a = *(const bf16x8*)&lds.A[(lr << 7) + ((gi ^ lr) << 3)];
#pragma unroll
    for (int j = 0; j < 2; ++j) {
      int col = (w << 5) + (j << 4) + lr;
      bf16x8 b = *(const bf16x8*)&WhImg[(col << 7) + (gi << 3)];
      c[j] = __builtin_amdgcn_mfma_f32_16x16x32_bf16(a, b, c[j], 0, 0, 0);
    }
  }
  __syncthreads();  // A consumed
  // bias + swizzled spill (f32x4-group xor row&7)
#pragma unroll
  for (int j = 0; j < 2; ++j) {
    int col = (w << 5) + (j << 4) + lr;
    float bias = bmsg[col];
    int g4 = col >> 2;
#pragma unroll
    for (int r = 0; r < 4; ++r) {
      int rr = (quad << 2) + r;
      lds.C[(rr << 7) + (((g4 ^ (rr & 7)) << 2) + (col & 3))] = c[j][r] + bias;
    }
  }
  __syncthreads();
  // repack: coalesced u16x8 store (16B/thread, 256B/row)
  {
    const f32x4* C4 = (const f32x4*)lds.C;
    f32x4 v0 = C4[(srow << 5) + (((sq << 1) | 0) ^ (srow & 7))];
    f32x4 v1 = C4[(srow << 5) + (((sq << 1) | 1) ^ (srow & 7))];
    u16x8 b = {f2b(v0[0]), f2b(v0[1]), f2b(v0[2]), f2b(v0[3]),
               f2b(v1[0]), f2b(v1[1]), f2b(v1[2]), f2b(v1[3])};
    *(u16x8*)&Hp[((size_t)(row0 + srow) << 7) + (sq << 3)] = b;
  }
}

// K3 (in-place): out = dropout(relu(LN((acc+boundary) @ W_lin + b_lin)))
// 16-row tiles (3125 blocks, ~8 blocks/CU), LN with 16 threads/row.
__global__ __launch_bounds__(256) void k_out(float* accout,
                                             const float* __restrict__ bnd,
                                             const u16* __restrict__ WlImg,
                                             const float* __restrict__ blin,
                                             const float* __restrict__ gam,
                                             const float* __restrict__ bet) {
  __shared__ union { u16 A[16 * 128]; float C[16 * 128]; } lds;  // 8 KB
  const int t = threadIdx.x;
  const int row0 = blockIdx.x << 4;
  const int srow = t >> 4, sq = t & 15;
  const int n = row0 + srow;
  {
    const float* ap = accout + ((size_t)n << 7) + (sq << 3);
    const float* bp = bnd + ((size_t)n << 7) + (sq << 3);
    f32x4 a0 = *(const f32x4*)ap, a1 = *(const f32x4*)(ap + 4);
    f32x4 b0 = *(const f32x4*)bp, b1 = *(const f32x4*)(bp + 4);
    f32x4 v0 = a0 + b0, v1 = a1 + b1;
    u16x8 b = {f2b(v0[0]), f2b(v0[1]), f2b(v0[2]), f2b(v0[3]),
               f2b(v1[0]), f2b(v1[1]), f2b(v1[2]), f2b(v1[3])};
    *(u16x8*)&lds.A[(srow << 7) + ((sq ^ srow) << 3)] = b;
  }
  __syncthreads();
  const int lane = t & 63, w = t >> 6;
  const int quad = lane >> 4, lr = lane & 15;
  f32x4 c[2];
#pragma unroll
  for (int j = 0; j < 2; ++j) { f32x4 z = {0.f, 0.f, 0.f, 0.f}; c[j] = z; }
#pragma unroll
  for (int ks = 0; ks < 128; ks += 32) {
    const int gi = (ks >> 3) + quad;
    bf16x8 a = *(const bf16x8*)&lds.A[(lr << 7) + ((gi ^ lr) << 3)];
#pragma unroll
    for (int j = 0; j < 2; ++j) {
      int col = (w << 5) + (j << 4) + lr;
      bf16x8 b = *(const bf16x8*)&WlImg[(col << 7) + (gi << 3)];
      c[j] = __builtin_amdgcn_mfma_f32_16x16x32_bf16(a, b, c[j], 0, 0, 0);
    }
  }
  __syncthreads();  // A consumed
  // bias + swizzled spill
#pragma unroll
  for (int j = 0; j < 2; ++j) {
    int col = (w << 5) + (j << 4) + lr;
    float bias = blin[col];
    int g4 = col >> 2;
#pragma unroll
    for (int r = 0; r < 4; ++r) {
      int rr = (quad << 2) + r;
      lds.C[(rr << 7) + (((g4 ^ (rr & 7)) << 2) + (col & 3))] = c[j][r] + bias;
    }
  }
  __syncthreads();
  // LN + relu + dropout: 16 threads/row, thread sq owns cols sq*8..+7
  const f32x4* C4 = (const f32x4*)lds.C;
  f32x4 x0 = C4[(srow << 5) + (((sq << 1) | 0) ^ (srow & 7))];
  f32x4 x1 = C4[(srow << 5) + (((sq << 1) | 1) ^ (srow & 7))];
  float s1 = 0.f, s2 = 0.f;
#pragma unroll
  for (int m = 0; m < 4; ++m) {
    s1 += x0[m] + x1[m];
    s2 += x0[m] * x0[m] + x1[m] * x1[m];
  }
  s1 += __shfl_xor(s1, 1, 64); s1 += __shfl_xor(s1, 2, 64);
  s1 += __shfl_xor(s1, 4, 64); s1 += __shfl_xor(s1, 8, 64);
  s2 += __shfl_xor(s2, 1, 64); s2 += __shfl_xor(s2, 2, 64);
  s2 += __shfl_xor(s2, 4, 64); s2 += __shfl_xor(s2, 8, 64);
  const float mean = s1 * 0.0078125f;
  const float var = s2 * 0.0078125f - mean * mean;
  const float inv = 1.0f / sqrtf(var + 1e-5f);
  const int d0 = sq << 3;
  f32x4 gm0 = *(const f32x4*)(gam + d0), gm1 = *(const f32x4*)(gam + d0 + 4);
  f32x4 bb0 = *(const f32x4*)(bet + d0), bb1 = *(const f32x4*)(bet + d0 + 4);
  f32x4 o0, o1;
#pragma unroll
  for (int m = 0; m < 4; ++m) {
    float y0 = fmaxf((x0[m] - mean) * inv * gm0[m] + bb0[m], 0.f);
    float y1 = fmaxf((x1[m] - mean) * inv * gm1[m] + bb1[m], 0.f);
    uint32_t j0 = ((uint32_t)n << 7) + (uint32_t)(d0 + m);
    uint32_t j1 = j0 + 4u;
    o0[m] = jax_keep(j0) ? (y0 * (1.0f / 0.9f)) : 0.0f;
    o1[m] = jax_keep(j1) ? (y1 * (1.0f / 0.9f)) : 0.0f;
  }
  *(f32x4*)(accout + ((size_t)n << 7) + d0) = o0;
  *(f32x4*)(accout + ((size_t)n << 7) + d0 + 4) = o1;
}

extern "C" void kernel_launch(void* const* d_in, const int* in_sizes, int n_in,
                              void* d_out, int out_size, void* d_ws, size_t ws_size,
                              hipStream_t stream) {
  (void)in_sizes; (void)n_in; (void)out_size; (void)ws_size;
  const float* hidden = (const float*)d_in[0];
  const int*   ei     = (const int*)d_in[1];
  const float* attr   = (const float*)d_in[2];
  const float* tim    = (const float*)d_in[3];
  const float* bnd    = (const float*)d_in[4];
  const float* Wmsg   = (const float*)d_in[5];
  const float* bmsg   = (const float*)d_in[6];
  const float* Wlin   = (const float*)d_in[7];
  const float* blin   = (const float*)d_in[8];
  const float* gam    = (const float*)d_in[9];
  const float* bet    = (const float*)d_in[10];

  float* acc = (float*)d_out;  // [N,128] f32 accumulator, finalized in-place

  char* ws = (char*)d_ws;
  u16*      Hp     = (u16*)(ws + 0);              // 12,800,000
  u16*      WhImg  = (u16*)(ws + 12800000);       //     32,768
  u16*      WcImg  = (u16*)(ws + 12832768);       //     16,384
  u16*      WlImg  = (u16*)(ws + 12849152);       //     32,768
  uint32_t* deg    = (uint32_t*)(ws + 12881920);  //    200,000
  uint32_t* cursor = (uint32_t*)(ws + 13081920);  //    200,000
  uint32_t* bsum   = (uint32_t*)(ws + 13281920);  //      1,024
  uint32_t* ex     = (uint32_t*)(ws + 13282944);  //    200,000
  u32x2*    psd    = (u32x2*)(ws + 13482944);     //  4,000,000 (NE*8)
  // total 17,482,944 bytes

  k_prep  <<<dim3(16), dim3(256), 0, stream>>>(Wmsg, Wlin, WhImg, WcImg, WlImg, deg);
  k_hp    <<<dim3(NT16), dim3(256), 0, stream>>>(hidden, WhImg, bmsg, ei, deg, Hp, acc);
  k_scan1 <<<dim3(NBLK_N), dim3(256), 0, stream>>>(deg, ex, bsum);
  k_scan23<<<dim3(NBLK_N), dim3(256), 0, stream>>>(bsum, ex, cursor);
  k_perm  <<<dim3((NE + 255) / 256), dim3(256), 0, stream>>>(ei, cursor, psd);
  k_edge3 <<<dim3(NEB), dim3(256), 0, stream>>>(psd, attr, tim, WcImg, Hp, acc);
  k_out   <<<dim3(NT16), dim3(256), 0, stream>>>(acc, bnd, WlImg, blin, gam, bet);
}